// Round 1
// baseline (1641.573 us; speedup 1.0000x reference)
//
#include <hip/hip_runtime.h>

// Problem constants
#define B_    128
#define HIDD  512
#define NCLS  7000
#define NPAD  7040
#define LSEQ  40
#define MROWS 5120   // LSEQ * B_

typedef __attribute__((ext_vector_type(8))) short bf16x8;
typedef __attribute__((ext_vector_type(4))) float f32x4;

__device__ __forceinline__ unsigned short f2bf(float x) {
  union { float f; unsigned u; } v; v.f = x;
  unsigned r = v.u + 0x7fffu + ((v.u >> 16) & 1u);   // RNE
  return (unsigned short)(r >> 16);
}
__device__ __forceinline__ float bf2f(unsigned short h) {
  union { unsigned u; float f; } v; v.u = ((unsigned)h) << 16;
  return v.f;
}
__device__ __forceinline__ float sigm(float x) { return 1.f / (1.f + __expf(-x)); }
__device__ __forceinline__ float tanh_f(float x) {
  float e = __expf(2.f * x);
  return 1.f - 2.f / (e + 1.f);
}

// ---------------- fp32 -> bf16 convert (vectorized x4) ----------------
__global__ __launch_bounds__(256) void k_cvt(const float* __restrict__ src,
                                             unsigned short* __restrict__ dst, int n4) {
  int i = blockIdx.x * 256 + threadIdx.x;
  if (i >= n4) return;
  float4 v = ((const float4*)src)[i];
  ushort4 o; o.x = f2bf(v.x); o.y = f2bf(v.y); o.z = f2bf(v.z); o.w = f2bf(v.w);
  ((ushort4*)dst)[i] = o;
}

// lin_w [7000][1024] -> bf16 padded [7040][1024] (pad rows zero)
__global__ __launch_bounds__(256) void k_linpad(const float* __restrict__ lw,
                                                unsigned short* __restrict__ dst) {
  int i = blockIdx.x * 256 + threadIdx.x;   // over 7040*1024/4
  int e = i * 4;
  int row = e >> 10;
  ushort4 o;
  if (row < NCLS) {
    float4 v = *(const float4*)(lw + (size_t)row * 1024 + (e & 1023));
    o.x = f2bf(v.x); o.y = f2bf(v.y); o.z = f2bf(v.z); o.w = f2bf(v.w);
  } else { o.x = 0; o.y = 0; o.z = 0; o.w = 0; }
  ((ushort4*)dst)[i] = o;
}

// teacher-forced inputs xts[l*128+b][512], bf16. l=0: hidden_en[-1]; l>0: embed_w[target[b][l-1]]
__global__ __launch_bounds__(256) void k_xts(const float* __restrict__ hidden_en,
                                             const float* __restrict__ embed_w,
                                             const int* __restrict__ target,
                                             unsigned short* __restrict__ xts) {
  int i = blockIdx.x * 256 + threadIdx.x;   // over 5120*512/4
  int e = i * 4;
  int r = e >> 9, col = e & 511;
  int l = r >> 7, b = r & 127;
  const float* src;
  if (l == 0) src = hidden_en + b * 512 + col;
  else        src = embed_w + (size_t)target[b * LSEQ + (l - 1)] * 512 + col;
  float4 v = *(const float4*)src;
  ushort4 o; o.x = f2bf(v.x); o.y = f2bf(v.y); o.z = f2bf(v.z); o.w = f2bf(v.w);
  ((ushort4*)xts)[i] = o;
}

// ---------------- bf16 MFMA GEMM: C[M][N] = A[M][K] @ Bw[N][K]^T + bias ----------------
// 128x128 block tile, BK=32, 4 waves (2x2 of 64x64), mfma_f32_16x16x32_bf16.
// MODE 0: out bf16 (xg), MODE 1: out fp32 (hem_all), MODE 2: logits -> d_out with (t,b) swizzle + n<7000 guard.
template <int MODE>
__global__ __launch_bounds__(256) void k_gemm(const unsigned short* __restrict__ A, int lda,
                                              const unsigned short* __restrict__ Bw, int ldb,
                                              const float* __restrict__ bias,
                                              void* __restrict__ outp, int ldc, int K) {
  __shared__ __align__(16) unsigned short As[128 * 32];
  __shared__ __align__(16) unsigned short Bs[128 * 32];
  const int tid = threadIdx.x;
  const int lane = tid & 63, wid = tid >> 6;
  const int wm = wid >> 1, wn = wid & 1;
  const int quad = lane >> 4, l16 = lane & 15;
  const int m0 = blockIdx.x * 128, n0 = blockIdx.y * 128;
  f32x4 acc[4][4];
#pragma unroll
  for (int i = 0; i < 4; i++)
#pragma unroll
    for (int j = 0; j < 4; j++) acc[i][j] = (f32x4){0.f, 0.f, 0.f, 0.f};

  const int r0 = tid >> 2, kq0 = (tid & 3) * 8;
  for (int k0 = 0; k0 < K; k0 += 32) {
#pragma unroll
    for (int s = 0; s < 2; s++) {
      int row = r0 + s * 64;
      *(bf16x8*)(As + row * 32 + kq0) = *(const bf16x8*)(A + (size_t)(m0 + row) * lda + k0 + kq0);
      *(bf16x8*)(Bs + row * 32 + kq0) = *(const bf16x8*)(Bw + (size_t)(n0 + row) * ldb + k0 + kq0);
    }
    __syncthreads();
    bf16x8 af[4], bfr[4];
#pragma unroll
    for (int i = 0; i < 4; i++)
      af[i] = *(const bf16x8*)(As + (wm * 64 + i * 16 + l16) * 32 + quad * 8);
#pragma unroll
    for (int j = 0; j < 4; j++)
      bfr[j] = *(const bf16x8*)(Bs + (wn * 64 + j * 16 + l16) * 32 + quad * 8);
#pragma unroll
    for (int i = 0; i < 4; i++)
#pragma unroll
      for (int j = 0; j < 4; j++)
        acc[i][j] = __builtin_amdgcn_mfma_f32_16x16x32_bf16(af[i], bfr[j], acc[i][j], 0, 0, 0);
    __syncthreads();
  }
  // epilogue: D layout col=lane&15, row=quad*4+r  [verified m89/m91]
#pragma unroll
  for (int i = 0; i < 4; i++) {
    int mbase = m0 + wm * 64 + i * 16 + quad * 4;
#pragma unroll
    for (int j = 0; j < 4; j++) {
      int n = n0 + wn * 64 + j * 16 + l16;
#pragma unroll
      for (int r = 0; r < 4; r++) {
        float v = acc[i][j][r];
        int m = mbase + r;
        if (MODE == 0) {
          ((unsigned short*)outp)[(size_t)m * ldc + n] = f2bf(v + bias[n]);
        } else if (MODE == 1) {
          ((float*)outp)[(size_t)m * ldc + n] = v + bias[n];
        } else {
          if (n < NCLS) {
            int t = m >> 7, b = m & 127;
            ((float*)outp)[((size_t)(b * LSEQ + t)) * NCLS + n] = v + bias[n];
          }
        }
      }
    }
  }
}

// ---------------- sequential LSTM step: gates = xg[t] + h_prev @ W_hh^T + b_hh -> (h,c) ----------------
// grid 256 blocks: 8 m-tiles(16) x 32 j-tiles(16). thread = (mi,ji) computes all 4 gates of (m,j).
__global__ __launch_bounds__(256) void k_gates(const float* __restrict__ h_prev,
                                               float* __restrict__ h_new,
                                               float* __restrict__ c_buf,
                                               const unsigned short* __restrict__ xg,
                                               const float* __restrict__ W_hh,
                                               const float* __restrict__ b_hh,
                                               unsigned short* __restrict__ hatt, int t) {
  __shared__ float h_s[16][68];
  __shared__ float W_s[64][68];
  const int tid = threadIdx.x;
  const int mt = blockIdx.x >> 5, jt = blockIdx.x & 31;
  const int m0 = mt * 16, j0 = jt * 16;
  const int mi = tid >> 4, ji = tid & 15;
  float a0 = 0.f, a1 = 0.f, a2 = 0.f, a3 = 0.f;
  if (t > 0) {
    for (int k0 = 0; k0 < 512; k0 += 64) {
      {
        int row = tid >> 4, c4 = (tid & 15) * 4;
        *(float4*)&h_s[row][c4] = *(const float4*)&h_prev[(m0 + row) * 512 + k0 + c4];
      }
#pragma unroll
      for (int w = 0; w < 4; w++) {
        int lin = w * 256 + tid;
        int row = lin >> 4, c4 = (lin & 15) * 4;
        int g = row >> 4, jj = row & 15;
        *(float4*)&W_s[row][c4] = *(const float4*)&W_hh[(size_t)((g << 9) + j0 + jj) * 512 + k0 + c4];
      }
      __syncthreads();
#pragma unroll 4
      for (int kk = 0; kk < 64; kk += 4) {
        float4 hv = *(const float4*)&h_s[mi][kk];
        float4 w0 = *(const float4*)&W_s[ji][kk];
        float4 w1 = *(const float4*)&W_s[16 + ji][kk];
        float4 w2 = *(const float4*)&W_s[32 + ji][kk];
        float4 w3 = *(const float4*)&W_s[48 + ji][kk];
        a0 += hv.x * w0.x + hv.y * w0.y + hv.z * w0.z + hv.w * w0.w;
        a1 += hv.x * w1.x + hv.y * w1.y + hv.z * w1.z + hv.w * w1.w;
        a2 += hv.x * w2.x + hv.y * w2.y + hv.z * w2.z + hv.w * w2.w;
        a3 += hv.x * w3.x + hv.y * w3.y + hv.z * w3.z + hv.w * w3.w;
      }
      __syncthreads();
    }
  }
  const int m = m0 + mi, j = j0 + ji;
  const size_t r = (size_t)t * 128 + m;
  a0 += bf2f(xg[r * 2048 + j])          + b_hh[j];
  a1 += bf2f(xg[r * 2048 + 512 + j])    + b_hh[512 + j];
  a2 += bf2f(xg[r * 2048 + 1024 + j])   + b_hh[1024 + j];
  a3 += bf2f(xg[r * 2048 + 1536 + j])   + b_hh[1536 + j];
  float ig = sigm(a0), fg = sigm(a1), gg = tanh_f(a2), og = sigm(a3);
  float c_old = (t > 0) ? c_buf[m * 512 + j] : 0.f;
  float c = fg * c_old + ig * gg;
  float h = og * tanh_f(c);
  c_buf[m * 512 + j] = c;
  h_new[m * 512 + j] = h;
  hatt[r * 1024 + j] = f2bf(h);
}

// ---------------- batched attention feature: s[t,b,p] = sum_c w_c * tanh(x_em[b,c,p] + hem[t,b,c]) ----------------
// grid = 40*128*2 blocks: (t, b, p-half); 256 threads = 128 p x 2 c-halves
__global__ __launch_bounds__(256) void k_feat(const float* __restrict__ hem_all,
                                              const unsigned short* __restrict__ xem,
                                              const float* __restrict__ attw_w,
                                              float* __restrict__ s_all) {
  __shared__ float hemL[512], wL[512], sp[2][128];
  const int tid = threadIdx.x;
  const int t = blockIdx.x >> 8;
  const int rem = blockIdx.x & 255;
  const int b = rem >> 1, ph = rem & 1;
  const size_t hrow = ((size_t)t * 128 + b) * 512;
  hemL[tid] = hem_all[hrow + tid];
  hemL[256 + tid] = hem_all[hrow + 256 + tid];
  wL[tid] = attw_w[tid];
  wL[256 + tid] = attw_w[256 + tid];
  __syncthreads();
  const int pl = tid & 127, ch = tid >> 7;
  const int p = ph * 128 + pl;
  const unsigned short* xp = xem + ((size_t)b * 512 + ch * 256) * 256 + p;
  float acc = 0.f;
#pragma unroll 4
  for (int ci = 0; ci < 256; ci++) {
    int c = ch * 256 + ci;
    float x = bf2f(xp[(size_t)ci * 256]);
    acc += wL[c] * tanh_f(x + hemL[c]);
  }
  sp[ch][pl] = acc;
  __syncthreads();
  if (ch == 0)
    s_all[((size_t)t * 128 + b) * 256 + p] = sp[0][pl] + sp[1][pl];
}

// ---------------- softmax over p (per t,b) + att[t,b,d] = sum_p alpha * att_x_em[b,p,d] ----------------
// grid 256 blocks: (b, d-half of 256). atx read once total.
__global__ __launch_bounds__(256) void k_att(const float* __restrict__ s_all,
                                             const float* __restrict__ atx,
                                             unsigned short* __restrict__ hatt) {
  __shared__ float sL[40][257];
  __shared__ float zinv[40];
  const int tid = threadIdx.x;
  const int b = blockIdx.x >> 1, dh = blockIdx.x & 1;
  for (int i = tid; i < 40 * 256; i += 256) {
    int t = i >> 8, p = i & 255;
    sL[t][p] = s_all[((size_t)t * 128 + b) * 256 + p];
  }
  __syncthreads();
  if (tid < 40) {
    int t = tid;
    float mx = -1e30f;
    for (int p = 0; p < 256; p++) mx = fmaxf(mx, sL[t][p]);
    float z = 0.f;
    for (int p = 0; p < 256; p++) { float e = __expf(sL[t][p] - mx); sL[t][p] = e; z += e; }
    zinv[t] = 1.f / z;
  }
  __syncthreads();
  float acc[40];
#pragma unroll
  for (int t = 0; t < 40; t++) acc[t] = 0.f;
  const int d = dh * 256 + tid;
  const float* ap = atx + (size_t)b * 256 * 512 + d;
  for (int p = 0; p < 256; p++) {
    float av = ap[(size_t)p * 512];
#pragma unroll
    for (int t = 0; t < 40; t++) acc[t] += sL[t][p] * av;
  }
#pragma unroll
  for (int t = 0; t < 40; t++) {
    float v = acc[t] * zinv[t];
    hatt[((size_t)t * 128 + b) * 1024 + 512 + d] = f2bf(v);
  }
}

// ---------------- in-place log_softmax over rows of 7000 in d_out ----------------
__global__ __launch_bounds__(256) void k_lsm(float* __restrict__ out) {
  __shared__ float buf[7000];
  __shared__ float red[256];
  const int tid = threadIdx.x;
  float* pr = out + (size_t)blockIdx.x * NCLS;
  for (int i = tid * 4; i < NCLS; i += 1024)
    *(float4*)&buf[i] = *(const float4*)&pr[i];
  __syncthreads();
  float mx = -1e30f;
  for (int i = tid; i < NCLS; i += 256) mx = fmaxf(mx, buf[i]);
  red[tid] = mx; __syncthreads();
  for (int s = 128; s > 0; s >>= 1) { if (tid < s) red[tid] = fmaxf(red[tid], red[tid + s]); __syncthreads(); }
  mx = red[0]; __syncthreads();
  float sum = 0.f;
  for (int i = tid; i < NCLS; i += 256) sum += __expf(buf[i] - mx);
  red[tid] = sum; __syncthreads();
  for (int s = 128; s > 0; s >>= 1) { if (tid < s) red[tid] += red[tid + s]; __syncthreads(); }
  float lse = mx + __logf(red[0]);
  for (int i = tid * 4; i < NCLS; i += 1024) {
    float4 v = *(const float4*)&buf[i];
    v.x -= lse; v.y -= lse; v.z -= lse; v.w -= lse;
    *(float4*)&pr[i] = v;
  }
}

extern "C" void kernel_launch(void* const* d_in, const int* in_sizes, int n_in,
                              void* d_out, int out_size, void* d_ws, size_t ws_size,
                              hipStream_t stream) {
  const float* hidden_en = (const float*)d_in[0];
  const float* x_em      = (const float*)d_in[1];
  const float* att_x     = (const float*)d_in[2];
  const int*   target    = (const int*)d_in[3];
  const float* embed_w   = (const float*)d_in[6];
  const float* W_ih      = (const float*)d_in[7];
  const float* W_hh      = (const float*)d_in[8];
  const float* b_ih      = (const float*)d_in[9];
  const float* b_hh      = (const float*)d_in[10];
  const float* hem_w     = (const float*)d_in[11];
  const float* hem_b     = (const float*)d_in[12];
  const float* attw_w    = (const float*)d_in[13];
  const float* lin_w     = (const float*)d_in[15];
  const float* lin_b     = (const float*)d_in[16];
  float* out = (float*)d_out;
  (void)in_sizes; (void)n_in; (void)out_size; (void)ws_size;

  char* w = (char*)d_ws;
  size_t off = 0;
  auto alloc = [&](size_t bytes) { char* p = w + off; off = (off + bytes + 255) & ~(size_t)255; return p; };
  unsigned short* xts  = (unsigned short*)alloc((size_t)MROWS * 512 * 2);
  unsigned short* wih  = (unsigned short*)alloc((size_t)2048 * 512 * 2);
  unsigned short* xg   = (unsigned short*)alloc((size_t)MROWS * 2048 * 2);
  unsigned short* hemw = (unsigned short*)alloc((size_t)512 * 512 * 2);
  unsigned short* linw = (unsigned short*)alloc((size_t)NPAD * 1024 * 2);
  unsigned short* xem  = (unsigned short*)alloc((size_t)128 * 512 * 256 * 2);
  unsigned short* hatt = (unsigned short*)alloc((size_t)MROWS * 1024 * 2);
  float* h0      = (float*)alloc((size_t)128 * 512 * 4);
  float* h1      = (float*)alloc((size_t)128 * 512 * 4);
  float* cb      = (float*)alloc((size_t)128 * 512 * 4);
  float* hem_all = (float*)alloc((size_t)MROWS * 512 * 4);
  float* s_all   = (float*)alloc((size_t)MROWS * 256 * 4);

  // --- precompute / conversions ---
  k_cvt<<<1024, 256, 0, stream>>>(W_ih, wih, 2048 * 512 / 4);
  k_cvt<<<256, 256, 0, stream>>>(hem_w, hemw, 512 * 512 / 4);
  k_cvt<<<16384, 256, 0, stream>>>(x_em, xem, 128 * 512 * 256 / 4);
  k_linpad<<<NPAD * 1024 / 4 / 256, 256, 0, stream>>>(lin_w, linw);
  k_xts<<<MROWS * 512 / 4 / 256, 256, 0, stream>>>(hidden_en, embed_w, target, xts);
  // xg_all = xts @ W_ih^T + b_ih  (bf16 out)
  k_gemm<0><<<dim3(40, 16), 256, 0, stream>>>(xts, 512, wih, 512, b_ih, xg, 2048, 512);

  // --- sequential LSTM scan (attention has no feedback into recurrence) ---
  for (int t = 0; t < LSEQ; t++) {
    const float* hp = (t & 1) ? h0 : h1;
    float* hn = (t & 1) ? h1 : h0;
    k_gates<<<256, 256, 0, stream>>>(hp, hn, cb, xg, W_hh, b_hh, hatt, t);
  }

  // --- batched attention over all 40 steps ---
  k_gemm<1><<<dim3(40, 4), 256, 0, stream>>>(hatt, 1024, hemw, 512, hem_b, hem_all, 512, 512);
  k_feat<<<LSEQ * 256, 256, 0, stream>>>(hem_all, xem, attw_w, s_all);
  k_att<<<256, 256, 0, stream>>>(s_all, att_x, hatt);

  // --- logits + log_softmax ---
  k_gemm<2><<<dim3(40, 55), 256, 0, stream>>>(hatt, 1024, linw, 1024, lin_b, out, NCLS, 1024);
  k_lsm<<<MROWS, 256, 0, stream>>>(out);
}

// Round 2
// 1394.592 us; speedup vs baseline: 1.1771x; 1.1771x over previous
//
#include <hip/hip_runtime.h>

// Problem constants
#define B_    128
#define HIDD  512
#define NCLS  7000
#define NPAD  7040
#define LSEQ  40
#define MROWS 5120   // LSEQ * B_
#define TT    10     // t-steps per k_feat block (40 = 4 * 10)

typedef __attribute__((ext_vector_type(8))) short bf16x8;
typedef __attribute__((ext_vector_type(4))) float f32x4;

__device__ __forceinline__ unsigned short f2bf(float x) {
  union { float f; unsigned u; } v; v.f = x;
  unsigned r = v.u + 0x7fffu + ((v.u >> 16) & 1u);   // RNE
  return (unsigned short)(r >> 16);
}
__device__ __forceinline__ float bf2f(unsigned short h) {
  union { unsigned u; float f; } v; v.u = ((unsigned)h) << 16;
  return v.f;
}
__device__ __forceinline__ float sigm(float x) { return 1.f / (1.f + __expf(-x)); }
__device__ __forceinline__ float tanh_f(float x) {
  float e = __expf(2.f * x);
  return 1.f - 2.f / (e + 1.f);
}
__device__ __forceinline__ float rcp_f(float x) { return __builtin_amdgcn_rcpf(x); }

// ---------------- fp32 -> bf16 convert (vectorized x4) ----------------
__global__ __launch_bounds__(256) void k_cvt(const float* __restrict__ src,
                                             unsigned short* __restrict__ dst, int n4) {
  int i = blockIdx.x * 256 + threadIdx.x;
  if (i >= n4) return;
  float4 v = ((const float4*)src)[i];
  ushort4 o; o.x = f2bf(v.x); o.y = f2bf(v.y); o.z = f2bf(v.z); o.w = f2bf(v.w);
  ((ushort4*)dst)[i] = o;
}

// x_em fp32 -> Ex = exp(2*x) bf16 (same [b][c][p] layout)
__global__ __launch_bounds__(256) void k_expcvt(const float* __restrict__ src,
                                                unsigned short* __restrict__ dst, int n4) {
  int i = blockIdx.x * 256 + threadIdx.x;
  if (i >= n4) return;
  float4 v = ((const float4*)src)[i];
  ushort4 o;
  o.x = f2bf(__expf(2.f * v.x)); o.y = f2bf(__expf(2.f * v.y));
  o.z = f2bf(__expf(2.f * v.z)); o.w = f2bf(__expf(2.f * v.w));
  ((ushort4*)dst)[i] = o;
}

// lin_w [7000][1024] -> bf16 padded [7040][1024] (pad rows zero)
__global__ __launch_bounds__(256) void k_linpad(const float* __restrict__ lw,
                                                unsigned short* __restrict__ dst) {
  int i = blockIdx.x * 256 + threadIdx.x;   // over 7040*1024/4
  int e = i * 4;
  int row = e >> 10;
  ushort4 o;
  if (row < NCLS) {
    float4 v = *(const float4*)(lw + (size_t)row * 1024 + (e & 1023));
    o.x = f2bf(v.x); o.y = f2bf(v.y); o.z = f2bf(v.z); o.w = f2bf(v.w);
  } else { o.x = 0; o.y = 0; o.z = 0; o.w = 0; }
  ((ushort4*)dst)[i] = o;
}

// teacher-forced inputs xts[l*128+b][512], bf16. l=0: hidden_en[-1]; l>0: embed_w[target[b][l-1]]
__global__ __launch_bounds__(256) void k_xts(const float* __restrict__ hidden_en,
                                             const float* __restrict__ embed_w,
                                             const int* __restrict__ target,
                                             unsigned short* __restrict__ xts) {
  int i = blockIdx.x * 256 + threadIdx.x;   // over 5120*512/4
  int e = i * 4;
  int r = e >> 9, col = e & 511;
  int l = r >> 7, b = r & 127;
  const float* src;
  if (l == 0) src = hidden_en + b * 512 + col;
  else        src = embed_w + (size_t)target[b * LSEQ + (l - 1)] * 512 + col;
  float4 v = *(const float4*)src;
  ushort4 o; o.x = f2bf(v.x); o.y = f2bf(v.y); o.z = f2bf(v.z); o.w = f2bf(v.w);
  ((ushort4*)xts)[i] = o;
}

// ---------------- bf16 MFMA GEMM: C[M][N] = A[M][K] @ Bw[N][K]^T + bias ----------------
// 128x128 block tile, BK=32, 4 waves (2x2 of 64x64), mfma_f32_16x16x32_bf16.
// MODE 0: out bf16 (xg). MODE 2: logits -> d_out with (t,b) swizzle + n<7000 guard.
// MODE 3: out fp32 = exp(2*(v+bias))  (Eh for attention).
template <int MODE>
__global__ __launch_bounds__(256) void k_gemm(const unsigned short* __restrict__ A, int lda,
                                              const unsigned short* __restrict__ Bw, int ldb,
                                              const float* __restrict__ bias,
                                              void* __restrict__ outp, int ldc, int K) {
  __shared__ __align__(16) unsigned short As[128 * 32];
  __shared__ __align__(16) unsigned short Bs[128 * 32];
  const int tid = threadIdx.x;
  const int lane = tid & 63, wid = tid >> 6;
  const int wm = wid >> 1, wn = wid & 1;
  const int quad = lane >> 4, l16 = lane & 15;
  const int m0 = blockIdx.x * 128, n0 = blockIdx.y * 128;
  f32x4 acc[4][4];
#pragma unroll
  for (int i = 0; i < 4; i++)
#pragma unroll
    for (int j = 0; j < 4; j++) acc[i][j] = (f32x4){0.f, 0.f, 0.f, 0.f};

  const int r0 = tid >> 2, kq0 = (tid & 3) * 8;
  for (int k0 = 0; k0 < K; k0 += 32) {
#pragma unroll
    for (int s = 0; s < 2; s++) {
      int row = r0 + s * 64;
      *(bf16x8*)(As + row * 32 + kq0) = *(const bf16x8*)(A + (size_t)(m0 + row) * lda + k0 + kq0);
      *(bf16x8*)(Bs + row * 32 + kq0) = *(const bf16x8*)(Bw + (size_t)(n0 + row) * ldb + k0 + kq0);
    }
    __syncthreads();
    bf16x8 af[4], bfr[4];
#pragma unroll
    for (int i = 0; i < 4; i++)
      af[i] = *(const bf16x8*)(As + (wm * 64 + i * 16 + l16) * 32 + quad * 8);
#pragma unroll
    for (int j = 0; j < 4; j++)
      bfr[j] = *(const bf16x8*)(Bs + (wn * 64 + j * 16 + l16) * 32 + quad * 8);
#pragma unroll
    for (int i = 0; i < 4; i++)
#pragma unroll
      for (int j = 0; j < 4; j++)
        acc[i][j] = __builtin_amdgcn_mfma_f32_16x16x32_bf16(af[i], bfr[j], acc[i][j], 0, 0, 0);
    __syncthreads();
  }
  // epilogue: D layout col=lane&15, row=quad*4+r  [verified m89/m91]
#pragma unroll
  for (int i = 0; i < 4; i++) {
    int mbase = m0 + wm * 64 + i * 16 + quad * 4;
#pragma unroll
    for (int j = 0; j < 4; j++) {
      int n = n0 + wn * 64 + j * 16 + l16;
#pragma unroll
      for (int r = 0; r < 4; r++) {
        float v = acc[i][j][r];
        int m = mbase + r;
        if (MODE == 0) {
          ((unsigned short*)outp)[(size_t)m * ldc + n] = f2bf(v + bias[n]);
        } else if (MODE == 3) {
          ((float*)outp)[(size_t)m * ldc + n] = __expf(2.f * (v + bias[n]));
        } else {
          if (n < NCLS) {
            int t = m >> 7, b = m & 127;
            ((float*)outp)[((size_t)(b * LSEQ + t)) * NCLS + n] = v + bias[n];
          }
        }
      }
    }
  }
}

// ---------------- sequential LSTM step: gates = xg[t] + h_prev @ W_hh^T + b_hh -> (h,c) ----------------
__global__ __launch_bounds__(256) void k_gates(const float* __restrict__ h_prev,
                                               float* __restrict__ h_new,
                                               float* __restrict__ c_buf,
                                               const unsigned short* __restrict__ xg,
                                               const float* __restrict__ W_hh,
                                               const float* __restrict__ b_hh,
                                               unsigned short* __restrict__ hatt, int t) {
  __shared__ float h_s[16][68];
  __shared__ float W_s[64][68];
  const int tid = threadIdx.x;
  const int mt = blockIdx.x >> 5, jt = blockIdx.x & 31;
  const int m0 = mt * 16, j0 = jt * 16;
  const int mi = tid >> 4, ji = tid & 15;
  float a0 = 0.f, a1 = 0.f, a2 = 0.f, a3 = 0.f;
  if (t > 0) {
    for (int k0 = 0; k0 < 512; k0 += 64) {
      {
        int row = tid >> 4, c4 = (tid & 15) * 4;
        *(float4*)&h_s[row][c4] = *(const float4*)&h_prev[(m0 + row) * 512 + k0 + c4];
      }
#pragma unroll
      for (int w = 0; w < 4; w++) {
        int lin = w * 256 + tid;
        int row = lin >> 4, c4 = (lin & 15) * 4;
        int g = row >> 4, jj = row & 15;
        *(float4*)&W_s[row][c4] = *(const float4*)&W_hh[(size_t)((g << 9) + j0 + jj) * 512 + k0 + c4];
      }
      __syncthreads();
#pragma unroll 4
      for (int kk = 0; kk < 64; kk += 4) {
        float4 hv = *(const float4*)&h_s[mi][kk];
        float4 w0 = *(const float4*)&W_s[ji][kk];
        float4 w1 = *(const float4*)&W_s[16 + ji][kk];
        float4 w2 = *(const float4*)&W_s[32 + ji][kk];
        float4 w3 = *(const float4*)&W_s[48 + ji][kk];
        a0 += hv.x * w0.x + hv.y * w0.y + hv.z * w0.z + hv.w * w0.w;
        a1 += hv.x * w1.x + hv.y * w1.y + hv.z * w1.z + hv.w * w1.w;
        a2 += hv.x * w2.x + hv.y * w2.y + hv.z * w2.z + hv.w * w2.w;
        a3 += hv.x * w3.x + hv.y * w3.y + hv.z * w3.z + hv.w * w3.w;
      }
      __syncthreads();
    }
  }
  const int m = m0 + mi, j = j0 + ji;
  const size_t r = (size_t)t * 128 + m;
  a0 += bf2f(xg[r * 2048 + j])          + b_hh[j];
  a1 += bf2f(xg[r * 2048 + 512 + j])    + b_hh[512 + j];
  a2 += bf2f(xg[r * 2048 + 1024 + j])   + b_hh[1024 + j];
  a3 += bf2f(xg[r * 2048 + 1536 + j])   + b_hh[1536 + j];
  float ig = sigm(a0), fg = sigm(a1), gg = tanh_f(a2), og = sigm(a3);
  float c_old = (t > 0) ? c_buf[m * 512 + j] : 0.f;
  float c = fg * c_old + ig * gg;
  float h = og * tanh_f(c);
  c_buf[m * 512 + j] = c;
  h_new[m * 512 + j] = h;
  hatt[r * 1024 + j] = f2bf(h);
}

// ---------------- attention scores via exp-factorized tanh ----------------
// tanh(x+h) = 1 - 2/(Ex*Eh+1); softmax is shift-invariant => s = -2 * sum_c w_c * rcp(Ex*Eh+1)
// grid: 4 t-groups x 128 b = 512 blocks; 256 threads = one p each; TT=10 t-steps reuse each Ex load.
__global__ __launch_bounds__(256) void k_feat(const float* __restrict__ Eh,
                                              const unsigned short* __restrict__ Ex,
                                              const float* __restrict__ attw_w,
                                              float* __restrict__ s_all) {
  __shared__ float EhL[TT][512];
  __shared__ float wL[512];
  const int tid = threadIdx.x;
  const int tg = blockIdx.x >> 7, b = blockIdx.x & 127;
  const int t0 = tg * TT;
  for (int i = tid * 4; i < TT * 512; i += 1024) {
    int t = i >> 9, c = i & 511;
    *(float4*)&EhL[t][c] = *(const float4*)&Eh[((size_t)(t0 + t) * 128 + b) * 512 + c];
  }
  if (tid < 128) *(float4*)&wL[tid * 4] = *(const float4*)&attw_w[tid * 4];
  __syncthreads();
  const int p = tid;
  const unsigned short* xp = Ex + (size_t)b * 512 * 256 + p;
  float acc[TT];
#pragma unroll
  for (int t = 0; t < TT; t++) acc[t] = 0.f;
  for (int c0 = 0; c0 < 512; c0 += 4) {
    float ex0 = bf2f(xp[(size_t)(c0 + 0) * 256]);
    float ex1 = bf2f(xp[(size_t)(c0 + 1) * 256]);
    float ex2 = bf2f(xp[(size_t)(c0 + 2) * 256]);
    float ex3 = bf2f(xp[(size_t)(c0 + 3) * 256]);
    float4 wv = *(const float4*)&wL[c0];
#pragma unroll
    for (int t = 0; t < TT; t++) {
      float4 eh = *(const float4*)&EhL[t][c0];
      acc[t] = __builtin_fmaf(wv.x, rcp_f(__builtin_fmaf(ex0, eh.x, 1.f)), acc[t]);
      acc[t] = __builtin_fmaf(wv.y, rcp_f(__builtin_fmaf(ex1, eh.y, 1.f)), acc[t]);
      acc[t] = __builtin_fmaf(wv.z, rcp_f(__builtin_fmaf(ex2, eh.z, 1.f)), acc[t]);
      acc[t] = __builtin_fmaf(wv.w, rcp_f(__builtin_fmaf(ex3, eh.w, 1.f)), acc[t]);
    }
  }
#pragma unroll
  for (int t = 0; t < TT; t++)
    s_all[((size_t)(t0 + t) * 128 + b) * 256 + p] = -2.f * acc[t];
}

// ---------------- softmax over p (per t,b) + att[t,b,d] = sum_p alpha * att_x_em[b,p,d] ----------------
__global__ __launch_bounds__(256) void k_att(const float* __restrict__ s_all,
                                             const float* __restrict__ atx,
                                             unsigned short* __restrict__ hatt) {
  __shared__ float sL[40][257];
  __shared__ float zinv[40];
  const int tid = threadIdx.x;
  const int b = blockIdx.x >> 1, dh = blockIdx.x & 1;
  for (int i = tid; i < 40 * 256; i += 256) {
    int t = i >> 8, p = i & 255;
    sL[t][p] = s_all[((size_t)t * 128 + b) * 256 + p];
  }
  __syncthreads();
  if (tid < 40) {
    int t = tid;
    float mx = -1e30f;
    for (int p = 0; p < 256; p++) mx = fmaxf(mx, sL[t][p]);
    float z = 0.f;
    for (int p = 0; p < 256; p++) { float e = __expf(sL[t][p] - mx); sL[t][p] = e; z += e; }
    zinv[t] = 1.f / z;
  }
  __syncthreads();
  float acc[40];
#pragma unroll
  for (int t = 0; t < 40; t++) acc[t] = 0.f;
  const int d = dh * 256 + tid;
  const float* ap = atx + (size_t)b * 256 * 512 + d;
  for (int p = 0; p < 256; p++) {
    float av = ap[(size_t)p * 512];
#pragma unroll
    for (int t = 0; t < 40; t++) acc[t] += sL[t][p] * av;
  }
#pragma unroll
  for (int t = 0; t < 40; t++) {
    float v = acc[t] * zinv[t];
    hatt[((size_t)t * 128 + b) * 1024 + 512 + d] = f2bf(v);
  }
}

// ---------------- in-place log_softmax over rows of 7000 in d_out ----------------
__global__ __launch_bounds__(256) void k_lsm(float* __restrict__ out) {
  __shared__ float buf[7000];
  __shared__ float red[256];
  const int tid = threadIdx.x;
  float* pr = out + (size_t)blockIdx.x * NCLS;
  for (int i = tid * 4; i < NCLS; i += 1024)
    *(float4*)&buf[i] = *(const float4*)&pr[i];
  __syncthreads();
  float mx = -1e30f;
  for (int i = tid; i < NCLS; i += 256) mx = fmaxf(mx, buf[i]);
  red[tid] = mx; __syncthreads();
  for (int s = 128; s > 0; s >>= 1) { if (tid < s) red[tid] = fmaxf(red[tid], red[tid + s]); __syncthreads(); }
  mx = red[0]; __syncthreads();
  float sum = 0.f;
  for (int i = tid; i < NCLS; i += 256) sum += __expf(buf[i] - mx);
  red[tid] = sum; __syncthreads();
  for (int s = 128; s > 0; s >>= 1) { if (tid < s) red[tid] += red[tid + s]; __syncthreads(); }
  float lse = mx + __logf(red[0]);
  for (int i = tid * 4; i < NCLS; i += 1024) {
    float4 v = *(const float4*)&buf[i];
    v.x -= lse; v.y -= lse; v.z -= lse; v.w -= lse;
    *(float4*)&pr[i] = v;
  }
}

extern "C" void kernel_launch(void* const* d_in, const int* in_sizes, int n_in,
                              void* d_out, int out_size, void* d_ws, size_t ws_size,
                              hipStream_t stream) {
  const float* hidden_en = (const float*)d_in[0];
  const float* x_em      = (const float*)d_in[1];
  const float* att_x     = (const float*)d_in[2];
  const int*   target    = (const int*)d_in[3];
  const float* embed_w   = (const float*)d_in[6];
  const float* W_ih      = (const float*)d_in[7];
  const float* W_hh      = (const float*)d_in[8];
  const float* b_ih      = (const float*)d_in[9];
  const float* b_hh      = (const float*)d_in[10];
  const float* hem_w     = (const float*)d_in[11];
  const float* hem_b     = (const float*)d_in[12];
  const float* attw_w    = (const float*)d_in[13];
  const float* lin_w     = (const float*)d_in[15];
  const float* lin_b     = (const float*)d_in[16];
  float* out = (float*)d_out;
  (void)in_sizes; (void)n_in; (void)out_size; (void)ws_size;

  char* w = (char*)d_ws;
  size_t off = 0;
  auto alloc = [&](size_t bytes) { char* p = w + off; off = (off + bytes + 255) & ~(size_t)255; return p; };
  unsigned short* xts  = (unsigned short*)alloc((size_t)MROWS * 512 * 2);
  unsigned short* wih  = (unsigned short*)alloc((size_t)2048 * 512 * 2);
  unsigned short* xg   = (unsigned short*)alloc((size_t)MROWS * 2048 * 2);
  unsigned short* hemw = (unsigned short*)alloc((size_t)512 * 512 * 2);
  unsigned short* linw = (unsigned short*)alloc((size_t)NPAD * 1024 * 2);
  unsigned short* xem  = (unsigned short*)alloc((size_t)128 * 512 * 256 * 2);  // Ex = exp(2*x_em) bf16
  unsigned short* hatt = (unsigned short*)alloc((size_t)MROWS * 1024 * 2);
  float* h0      = (float*)alloc((size_t)128 * 512 * 4);
  float* h1      = (float*)alloc((size_t)128 * 512 * 4);
  float* cb      = (float*)alloc((size_t)128 * 512 * 4);
  float* eh_all  = (float*)alloc((size_t)MROWS * 512 * 4);   // Eh = exp(2*hem)
  float* s_all   = (float*)alloc((size_t)MROWS * 256 * 4);

  // --- precompute / conversions ---
  k_cvt<<<1024, 256, 0, stream>>>(W_ih, wih, 2048 * 512 / 4);
  k_cvt<<<256, 256, 0, stream>>>(hem_w, hemw, 512 * 512 / 4);
  k_expcvt<<<16384, 256, 0, stream>>>(x_em, xem, 128 * 512 * 256 / 4);
  k_linpad<<<NPAD * 1024 / 4 / 256, 256, 0, stream>>>(lin_w, linw);
  k_xts<<<MROWS * 512 / 4 / 256, 256, 0, stream>>>(hidden_en, embed_w, target, xts);
  // xg_all = xts @ W_ih^T + b_ih  (bf16 out)
  k_gemm<0><<<dim3(40, 16), 256, 0, stream>>>(xts, 512, wih, 512, b_ih, xg, 2048, 512);

  // --- sequential LSTM scan (attention has no feedback into recurrence) ---
  for (int t = 0; t < LSEQ; t++) {
    const float* hp = (t & 1) ? h0 : h1;
    float* hn = (t & 1) ? h1 : h0;
    k_gates<<<256, 256, 0, stream>>>(hp, hn, cb, xg, W_hh, b_hh, hatt, t);
  }

  // --- batched attention over all 40 steps ---
  // Eh = exp(2*(h@hem_w^T + hem_b)) fused into GEMM epilogue (MODE 3)
  k_gemm<3><<<dim3(40, 4), 256, 0, stream>>>(hatt, 1024, hemw, 512, hem_b, eh_all, 512, 512);
  k_feat<<<512, 256, 0, stream>>>(eh_all, xem, attw_w, s_all);
  k_att<<<256, 256, 0, stream>>>(s_all, att_x, hatt);

  // --- logits + log_softmax ---
  k_gemm<2><<<dim3(40, 55), 256, 0, stream>>>(hatt, 1024, linw, 1024, lin_b, out, NCLS, 1024);
  k_lsm<<<MROWS, 256, 0, stream>>>(out);
}